// Round 6
// baseline (96.208 us; speedup 1.0000x reference)
//
#include <hip/hip_runtime.h>

// B=32, L=512, D=1024; 7 linear experts + identity, routed per token.
// Pipeline: route (fused count+offsets+slot, 1 workgroup) -> convW (f32->bf16)
// -> rowconv (gather+convert compact / identity copy) -> bf16 MFMA GEMM
// (256x256 tile, 4 waves, wave-tile 128x128, BK=64, XOR-swizzled LDS,
//  2-phase double-buffer, XCD-interleaved block map).

#define NTOK 16384
#define DDIM 1024
#define NEXP 7
#define BM 256
#define BN 256
#define BK 64
#define NKT (DDIM / BK)
#define NYMAX 72              // 9 per XCD * 8

// ws layout (int indices / byte offsets)
#define WI_OFFS   16          // [8]
#define WI_NTILES 32
#define WI_TABLE  64          // [72][2] {expert, crow0}
#define WI_CTOK   512         // [16384] slot -> token
#define WI_SMAP   (512 + 16384) // [16384] token -> slot (-1 = identity)
#define WS_ABF_B  1048576                       // 32 MB bf16 A (compact)
#define WS_WBF_B  (WS_ABF_B + NTOK * DDIM * 2)  // 14 MB bf16 W

typedef __attribute__((ext_vector_type(8))) short short8;
typedef __attribute__((ext_vector_type(4))) float f32x4;

__device__ __forceinline__ unsigned short f2bf(float f) {
    unsigned u = __float_as_uint(f);
    u += 0x7fff + ((u >> 16) & 1);
    return (unsigned short)(u >> 16);
}

__device__ __forceinline__ void gload16(const void* g, void* l) {
    __builtin_amdgcn_global_load_lds(
        (const __attribute__((address_space(1))) void*)g,
        (__attribute__((address_space(3))) void*)l, 16, 0, 0);
}

// Single workgroup: per-wave histogram -> prefix/table -> slot scatter.
__global__ __launch_bounds__(1024) void route_k(
    const int* __restrict__ type, int* __restrict__ wsi) {
    __shared__ int h[16][8];
    __shared__ int cur[16][NEXP];
    const int tid = threadIdx.x, wave = tid >> 6;

    if (tid < 128) ((int*)h)[tid] = 0;
    __syncthreads();

    int kv[16];
#pragma unroll
    for (int i = 0; i < 16; ++i) {
        kv[i] = type[i * 1024 + tid];
        if (kv[i] > 0) atomicAdd(&h[wave][kv[i]], 1);
    }
    __syncthreads();

    if (tid == 0) {
        int acc = 0, t = 0;
        for (int e = 0; e < NEXP; ++e) {
            wsi[WI_OFFS + e] = acc;
            int run = acc;
            for (int w = 0; w < 16; ++w) { cur[w][e] = run; run += h[w][e + 1]; }
            int nt = (run - acc + BM - 1) >> 8;
            for (int i = 0; i < nt; ++i) {
                wsi[WI_TABLE + 2 * t] = e;
                wsi[WI_TABLE + 2 * t + 1] = acc + i * BM;
                ++t;
            }
            acc = run;
        }
        wsi[WI_OFFS + NEXP] = acc;
        wsi[WI_NTILES] = t;
    }
    __syncthreads();

#pragma unroll
    for (int i = 0; i < 16; ++i) {
        int t = i * 1024 + tid, s = -1;
        if (kv[i] > 0) {
            s = atomicAdd(&cur[wave][kv[i] - 1], 1);
            wsi[WI_CTOK + s] = t;
        }
        wsi[WI_SMAP + t] = s;
    }
}

__global__ __launch_bounds__(256) void convW_k(
    const float* __restrict__ W, unsigned short* __restrict__ Wbf) {
    size_t i = ((size_t)blockIdx.x * 256 + threadIdx.x) * 16;
    const float4* src = (const float4*)(W + i);
    float4 v0 = src[0], v1 = src[1], v2 = src[2], v3 = src[3];
    short8 h0, h1;
    h0[0]=f2bf(v0.x); h0[1]=f2bf(v0.y); h0[2]=f2bf(v0.z); h0[3]=f2bf(v0.w);
    h0[4]=f2bf(v1.x); h0[5]=f2bf(v1.y); h0[6]=f2bf(v1.z); h0[7]=f2bf(v1.w);
    h1[0]=f2bf(v2.x); h1[1]=f2bf(v2.y); h1[2]=f2bf(v2.z); h1[3]=f2bf(v2.w);
    h1[4]=f2bf(v3.x); h1[5]=f2bf(v3.y); h1[6]=f2bf(v3.z); h1[7]=f2bf(v3.w);
    *(short8*)(Wbf + i) = h0;
    *(short8*)(Wbf + i + 8) = h1;
}

// One wave per token row: identity copy (f32->out) or gather+convert (bf16->Abf).
__global__ __launch_bounds__(256) void rowconv_k(
    const float* __restrict__ A, const int* __restrict__ wsi,
    unsigned short* __restrict__ Abf, float* __restrict__ out) {
    int wave = threadIdx.x >> 6, lane = threadIdx.x & 63;
    int t = blockIdx.x * 4 + wave;
    int s = wsi[WI_SMAP + t];
    const float4* src = (const float4*)(A + (size_t)t * DDIM);
    if (s < 0) {
        float4* d = (float4*)(out + (size_t)t * DDIM);
#pragma unroll
        for (int j = 0; j < 4; ++j) d[lane + j * 64] = src[lane + j * 64];
    } else {
        float4 v0 = src[lane * 4 + 0], v1 = src[lane * 4 + 1];
        float4 v2 = src[lane * 4 + 2], v3 = src[lane * 4 + 3];
        short8 h0, h1;
        h0[0]=f2bf(v0.x); h0[1]=f2bf(v0.y); h0[2]=f2bf(v0.z); h0[3]=f2bf(v0.w);
        h0[4]=f2bf(v1.x); h0[5]=f2bf(v1.y); h0[6]=f2bf(v1.z); h0[7]=f2bf(v1.w);
        h1[0]=f2bf(v2.x); h1[1]=f2bf(v2.y); h1[2]=f2bf(v2.z); h1[3]=f2bf(v2.w);
        h1[4]=f2bf(v3.x); h1[5]=f2bf(v3.y); h1[6]=f2bf(v3.z); h1[7]=f2bf(v3.w);
        unsigned short* d = Abf + (size_t)s * DDIM + lane * 16;
        *(short8*)d = h0;
        *(short8*)(d + 8) = h1;
    }
}

__global__ __launch_bounds__(256, 1) void gemm_k(
    const unsigned short* __restrict__ Abf,
    const unsigned short* __restrict__ Wbf,
    const float* __restrict__ bias, float* __restrict__ out,
    const int* __restrict__ wsi) {
    // XCD-interleaved: c = bid&7 = XCD; ty = (j>>2)*8+c, tx = j&3.
    const int bid = blockIdx.x;
    const int c = bid & 7, j = bid >> 3;
    const int ty = (j >> 2) * 8 + c;
    const int tx = j & 3;
    if (ty >= wsi[WI_NTILES]) return;
    const int* offs = wsi + WI_OFFS;
    const int* tab  = wsi + WI_TABLE;
    const int* ctok = wsi + WI_CTOK;
    const int e     = tab[2 * ty];
    const int crow0 = tab[2 * ty + 1];
    const int nend  = offs[e + 1];
    const int col0  = tx * BN;

    // dbuf, XOR-swizzled: LDS row r slot s (16B chunks) holds global chunk s^(r&7)
    __shared__ unsigned short As[2][BM * BK];   // 32 KB each
    __shared__ unsigned short Bs[2][BM * BK];

    const int tid = threadIdx.x, lane = tid & 63, wave = tid >> 6;
    const int wr = wave >> 1, wc = wave & 1;          // wave-tile 128x128
    const int srow8 = lane >> 3;                      // 0..7
    const int swz   = ((lane & 7) ^ srow8) * 8;       // inverse-swizzled src chunk

    const unsigned short* Wb = Wbf + (size_t)e * DDIM * DDIM;
    const unsigned short* aptr[8];
    const unsigned short* bptr[8];
#pragma unroll
    for (int p = 0; p < 8; ++p) {
        int r = min(crow0 + wave * 64 + p * 8 + srow8, NTOK - 1);
        aptr[p] = Abf + (size_t)r * DDIM + swz;
        bptr[p] = Wb + (size_t)(col0 + wave * 64 + p * 8 + srow8) * DDIM + swz;
    }

    f32x4 acc[8][8];
#pragma unroll
    for (int m = 0; m < 8; ++m)
#pragma unroll
        for (int nn = 0; nn < 8; ++nn) acc[m][nn] = (f32x4){0.f, 0.f, 0.f, 0.f};

    // prologue: stage K-tile 0 into buf 0 (each gload stages 8 rows of 128 B)
#pragma unroll
    for (int p = 0; p < 8; ++p)
        gload16(aptr[p], (char*)As[0] + (wave * 64 + p * 8) * 128);
#pragma unroll
    for (int p = 0; p < 8; ++p)
        gload16(bptr[p], (char*)Bs[0] + (wave * 64 + p * 8) * 128);
    __syncthreads();

    for (int kt = 0; kt < NKT; ++kt) {
        const int cur = kt & 1;
        if (kt + 1 < NKT) {
            const int k1 = (kt + 1) * BK;
#pragma unroll
            for (int p = 0; p < 8; ++p)
                gload16(aptr[p] + k1, (char*)As[cur ^ 1] + (wave * 64 + p * 8) * 128);
#pragma unroll
            for (int p = 0; p < 8; ++p)
                gload16(bptr[p] + k1, (char*)Bs[cur ^ 1] + (wave * 64 + p * 8) * 128);
        }
#pragma unroll
        for (int ks = 0; ks < 2; ++ks) {
            const int cbase = ks * 4 + (lane >> 4);          // k-chunk 0..7
            short8 af[8], bf[8];
#pragma unroll
            for (int m = 0; m < 8; ++m) {
                int row = wr * 128 + m * 16 + (lane & 15);
                af[m] = *(const short8*)&As[cur][row * BK + (cbase ^ (lane & 7)) * 8];
            }
#pragma unroll
            for (int nn = 0; nn < 8; ++nn) {
                int row = wc * 128 + nn * 16 + (lane & 15);
                bf[nn] = *(const short8*)&Bs[cur][row * BK + (cbase ^ (lane & 7)) * 8];
            }
#pragma unroll
            for (int m = 0; m < 8; ++m)
#pragma unroll
                for (int nn = 0; nn < 8; ++nn)
                    acc[m][nn] = __builtin_amdgcn_mfma_f32_16x16x32_bf16(
                        af[m], bf[nn], acc[m][nn], 0, 0, 0);
        }
        __syncthreads();
    }

    const int ccol  = lane & 15;
    const int crow4 = (lane >> 4) * 4;
    float bv[8];
#pragma unroll
    for (int nn = 0; nn < 8; ++nn)
        bv[nn] = bias[e * DDIM + col0 + wc * 128 + nn * 16 + ccol];

#pragma unroll
    for (int m = 0; m < 8; ++m) {
#pragma unroll
        for (int r = 0; r < 4; ++r) {
            int gr = crow0 + wr * 128 + m * 16 + crow4 + r;
            if (gr >= nend) continue;
            int tok = ctok[gr];
            float* orow = out + (size_t)tok * DDIM + col0 + wc * 128 + ccol;
#pragma unroll
            for (int nn = 0; nn < 8; ++nn)
                orow[nn * 16] = acc[m][nn][r] + bv[nn];
        }
    }
}

extern "C" void kernel_launch(void* const* d_in, const int* in_sizes, int n_in,
                              void* d_out, int out_size, void* d_ws, size_t ws_size,
                              hipStream_t stream) {
    const float* actions = (const float*)d_in[0];
    const int*   atype   = (const int*)d_in[1];
    const float* W       = (const float*)d_in[2];
    const float* bias    = (const float*)d_in[3];
    float* out = (float*)d_out;

    int* wsi = (int*)d_ws;
    unsigned short* Abf = (unsigned short*)((char*)d_ws + WS_ABF_B);
    unsigned short* Wbf = (unsigned short*)((char*)d_ws + WS_WBF_B);

    route_k<<<1, 1024, 0, stream>>>(atype, wsi);
    convW_k<<<1792, 256, 0, stream>>>(W, Wbf);
    rowconv_k<<<NTOK / 4, 256, 0, stream>>>(actions, wsi, Abf, out);
    gemm_k<<<NYMAX * 4, 256, 0, stream>>>(Abf, Wbf, bias, out, wsi);
}

// Round 7
// 88.211 us; speedup vs baseline: 1.0907x; 1.0907x over previous
//
#include <hip/hip_runtime.h>

// B=32, L=512, D=1024; 7 linear experts + identity, routed per token.
// Pipeline: route (fused count+offsets+slot, 1 wg) -> fusedconv (rowconv +
// convW in one grid) -> bf16 MFMA GEMM with 8-phase-style schedule:
// 256x256 tile, 8 waves (2Mx4N, per-wave 128x64), BK=64, XOR-swizzled LDS,
// double-buffer, counted vmcnt(8) (never 0 mid-loop), raw s_barrier phases,
// setprio around MFMA clusters, XCD-interleaved block map.

#define NTOK 16384
#define DDIM 1024
#define NEXP 7
#define BM 256
#define BN 256
#define BK 64
#define NKT (DDIM / BK)
#define NYMAX 72              // 9 per XCD * 8

// ws layout (int indices / byte offsets)
#define WI_OFFS   16          // [8]
#define WI_NTILES 32
#define WI_TABLE  64          // [72][2] {expert, crow0}
#define WI_CTOK   512         // [16384] slot -> token
#define WI_SMAP   (512 + 16384) // [16384] token -> slot (-1 = identity)
#define WS_ABF_B  1048576                       // 32 MB bf16 A (compact)
#define WS_WBF_B  (WS_ABF_B + NTOK * DDIM * 2)  // 14 MB bf16 W

typedef __attribute__((ext_vector_type(8))) short short8;
typedef __attribute__((ext_vector_type(4))) float f32x4;

__device__ __forceinline__ unsigned short f2bf(float f) {
    unsigned u = __float_as_uint(f);
    u += 0x7fff + ((u >> 16) & 1);
    return (unsigned short)(u >> 16);
}

__device__ __forceinline__ void gload16(const void* g, void* l) {
    __builtin_amdgcn_global_load_lds(
        (const __attribute__((address_space(1))) void*)g,
        (__attribute__((address_space(3))) void*)l, 16, 0, 0);
}

// Single workgroup: per-wave histogram -> prefix/table -> slot scatter.
__global__ __launch_bounds__(1024) void route_k(
    const int* __restrict__ type, int* __restrict__ wsi) {
    __shared__ int h[16][8];
    __shared__ int cur[16][NEXP];
    const int tid = threadIdx.x, wave = tid >> 6;

    if (tid < 128) ((int*)h)[tid] = 0;
    __syncthreads();

    int kv[16];
#pragma unroll
    for (int i = 0; i < 16; ++i) {
        kv[i] = type[i * 1024 + tid];
        if (kv[i] > 0) atomicAdd(&h[wave][kv[i]], 1);
    }
    __syncthreads();

    if (tid == 0) {
        int acc = 0, t = 0;
        for (int e = 0; e < NEXP; ++e) {
            wsi[WI_OFFS + e] = acc;
            int run = acc;
            for (int w = 0; w < 16; ++w) { cur[w][e] = run; run += h[w][e + 1]; }
            int nt = (run - acc + BM - 1) >> 8;
            for (int i = 0; i < nt; ++i) {
                wsi[WI_TABLE + 2 * t] = e;
                wsi[WI_TABLE + 2 * t + 1] = acc + i * BM;
                ++t;
            }
            acc = run;
        }
        wsi[WI_OFFS + NEXP] = acc;
        wsi[WI_NTILES] = t;
    }
    __syncthreads();

#pragma unroll
    for (int i = 0; i < 16; ++i) {
        int t = i * 1024 + tid, s = -1;
        if (kv[i] > 0) {
            s = atomicAdd(&cur[wave][kv[i] - 1], 1);
            wsi[WI_CTOK + s] = t;
        }
        wsi[WI_SMAP + t] = s;
    }
}

// blocks 0..4095: per-row gather+convert/identity; blocks 4096..5887: W conv.
__global__ __launch_bounds__(256) void fusedconv_k(
    const float* __restrict__ A, const int* __restrict__ wsi,
    const float* __restrict__ W, unsigned short* __restrict__ Wbf,
    unsigned short* __restrict__ Abf, float* __restrict__ out) {
    const int bid = blockIdx.x, tid = threadIdx.x;
    if (bid < 4096) {
        int wave = tid >> 6, lane = tid & 63;
        int t = bid * 4 + wave;
        int s = wsi[WI_SMAP + t];
        const float4* src = (const float4*)(A + (size_t)t * DDIM);
        if (s < 0) {
            float4* d = (float4*)(out + (size_t)t * DDIM);
#pragma unroll
            for (int j = 0; j < 4; ++j) d[lane + j * 64] = src[lane + j * 64];
        } else {
            float4 v0 = src[lane * 4 + 0], v1 = src[lane * 4 + 1];
            float4 v2 = src[lane * 4 + 2], v3 = src[lane * 4 + 3];
            short8 h0, h1;
            h0[0]=f2bf(v0.x); h0[1]=f2bf(v0.y); h0[2]=f2bf(v0.z); h0[3]=f2bf(v0.w);
            h0[4]=f2bf(v1.x); h0[5]=f2bf(v1.y); h0[6]=f2bf(v1.z); h0[7]=f2bf(v1.w);
            h1[0]=f2bf(v2.x); h1[1]=f2bf(v2.y); h1[2]=f2bf(v2.z); h1[3]=f2bf(v2.w);
            h1[4]=f2bf(v3.x); h1[5]=f2bf(v3.y); h1[6]=f2bf(v3.z); h1[7]=f2bf(v3.w);
            unsigned short* d = Abf + (size_t)s * DDIM + lane * 16;
            *(short8*)d = h0;
            *(short8*)(d + 8) = h1;
        }
    } else {
        size_t i = ((size_t)(bid - 4096) * 256 + tid) * 16;
        const float4* src = (const float4*)(W + i);
        float4 v0 = src[0], v1 = src[1], v2 = src[2], v3 = src[3];
        short8 h0, h1;
        h0[0]=f2bf(v0.x); h0[1]=f2bf(v0.y); h0[2]=f2bf(v0.z); h0[3]=f2bf(v0.w);
        h0[4]=f2bf(v1.x); h0[5]=f2bf(v1.y); h0[6]=f2bf(v1.z); h0[7]=f2bf(v1.w);
        h1[0]=f2bf(v2.x); h1[1]=f2bf(v2.y); h1[2]=f2bf(v2.z); h1[3]=f2bf(v2.w);
        h1[4]=f2bf(v3.x); h1[5]=f2bf(v3.y); h1[6]=f2bf(v3.z); h1[7]=f2bf(v3.w);
        *(short8*)(Wbf + i) = h0;
        *(short8*)(Wbf + i + 8) = h1;
    }
}

#define LDA8(SL)                                                   \
    _Pragma("unroll")                                              \
    for (int m = 0; m < 8; ++m)                                    \
        a8[m] = *(const short8*)(asb + m * 2048 + (SL));

#define LDB2(N0, SL)                                               \
    bA = *(const short8*)(bsb + (N0) * 2048 + (SL));               \
    bB = *(const short8*)(bsb + ((N0) + 1) * 2048 + (SL));

#define MFMA_PHASE(N0, N1)                                         \
    __builtin_amdgcn_s_barrier();                                  \
    asm volatile("s_waitcnt lgkmcnt(0)" ::: "memory");             \
    __builtin_amdgcn_sched_barrier(0);                             \
    __builtin_amdgcn_s_setprio(1);                                 \
    _Pragma("unroll")                                              \
    for (int m = 0; m < 8; ++m) {                                  \
        acc[m][N0] = __builtin_amdgcn_mfma_f32_16x16x32_bf16(      \
            a8[m], bA, acc[m][N0], 0, 0, 0);                       \
        acc[m][N1] = __builtin_amdgcn_mfma_f32_16x16x32_bf16(      \
            a8[m], bB, acc[m][N1], 0, 0, 0);                       \
    }                                                              \
    __builtin_amdgcn_s_setprio(0);                                 \
    __builtin_amdgcn_s_barrier();

__global__ __launch_bounds__(512, 2) void gemm_k(
    const unsigned short* __restrict__ Abf,
    const unsigned short* __restrict__ Wbf,
    const float* __restrict__ bias, float* __restrict__ out,
    const int* __restrict__ wsi) {
    // XCD-interleaved: c = bid&7 = XCD; ty = (j>>2)*8+c, tx = j&3.
    const int bid = blockIdx.x;
    const int c = bid & 7, j = bid >> 3;
    const int ty = (j >> 2) * 8 + c;
    const int tx = j & 3;
    if (ty >= wsi[WI_NTILES]) return;
    const int* offs = wsi + WI_OFFS;
    const int* tab  = wsi + WI_TABLE;
    const int* ctok = wsi + WI_CTOK;
    const int e     = tab[2 * ty];
    const int crow0 = tab[2 * ty + 1];
    const int nend  = offs[e + 1];
    const int col0  = tx * BN;

    // dbuf, XOR-swizzled: LDS row r chunk-slot s (16B) holds global chunk s^(r&7)
    __shared__ unsigned short As[2][BM * BK];   // 32 KB each
    __shared__ unsigned short Bs[2][BM * BK];

    const int tid = threadIdx.x, lane = tid & 63, wave = tid >> 6;
    const int wr = wave >> 2, wc = wave & 3;     // 2M x 4N; wave-tile 128x64
    const int lane15 = lane & 15;

    // staging: per wave 4 rounds x (8 rows x 8 chunks); lane -> (row,chunk)
    const int srow = lane >> 3;                          // 0..7
    const int schunk = ((lane & 7) ^ srow) * 8;          // inverse-swizzled src

    const unsigned short* Wb = Wbf + (size_t)e * DDIM * DDIM;
    const unsigned short* aSrc[4];
    const unsigned short* bSrc[4];
#pragma unroll
    for (int q = 0; q < 4; ++q) {
        int r = min(crow0 + q * 64 + wave * 8 + srow, NTOK - 1);
        aSrc[q] = Abf + (size_t)r * DDIM + schunk;
        bSrc[q] = Wb + (size_t)(col0 + q * 64 + wave * 8 + srow) * DDIM + schunk;
    }

    // ds_read bases and swizzled slot byte-offsets for ks=0 / ks=1
    const char* asRow = (const char*)As + wr * 16384 + lane15 * 128;
    const char* bsRow = (const char*)Bs + wc * 8192 + lane15 * 128;
    const int sl0 = (((lane >> 4)) ^ (lane & 7)) * 16;
    const int sl1 = ((4 | (lane >> 4)) ^ (lane & 7)) * 16;

    f32x4 acc[8][4];
#pragma unroll
    for (int m = 0; m < 8; ++m)
#pragma unroll
        for (int n = 0; n < 4; ++n) acc[m][n] = (f32x4){0.f, 0.f, 0.f, 0.f};

    // prologue: stage K-tile 0 into buf 0
#pragma unroll
    for (int q = 0; q < 4; ++q)
        gload16(aSrc[q], (char*)As + wave * 1024 + q * 8192);
#pragma unroll
    for (int q = 0; q < 4; ++q)
        gload16(bSrc[q], (char*)Bs + wave * 1024 + q * 8192);

#pragma unroll 2
    for (int kt = 0; kt < NKT; ++kt) {
        const int pof = (kt & 1) * 32768;
        if (kt + 1 < NKT) {           // burst-stage next K-tile into other buf
            const int ke = (kt + 1) * BK;
            const int qof = pof ^ 32768;
#pragma unroll
            for (int q = 0; q < 4; ++q)
                gload16(aSrc[q] + ke, (char*)As + qof + wave * 1024 + q * 8192);
#pragma unroll
            for (int q = 0; q < 4; ++q)
                gload16(bSrc[q] + ke, (char*)Bs + qof + wave * 1024 + q * 8192);
            asm volatile("s_waitcnt vmcnt(8)" ::: "memory");  // prev tile landed
        } else {
            asm volatile("s_waitcnt vmcnt(0)" ::: "memory");
        }
        __builtin_amdgcn_s_barrier();   // gate: buf(kt) resident for ALL waves

        const char* asb = asRow + pof;
        const char* bsb = bsRow + pof;
        short8 a8[8], bA, bB;
        // ph1: ks0, n={0,1}
        LDA8(sl0); LDB2(0, sl0);
        MFMA_PHASE(0, 1);
        // ph2: ks0, n={2,3}
        LDB2(2, sl0);
        MFMA_PHASE(2, 3);
        // ph3: ks1, n={2,3}
        LDA8(sl1); LDB2(2, sl1);
        MFMA_PHASE(2, 3);
        // ph4: ks1, n={0,1}
        LDB2(0, sl1);
        MFMA_PHASE(0, 1);
    }

    // epilogue: bias + gathered store (C/D: col=lane&15, row=(lane>>4)*4+r)
    const int crow4 = (lane >> 4) * 4;
    float bv[4];
#pragma unroll
    for (int n = 0; n < 4; ++n)
        bv[n] = bias[e * DDIM + col0 + wc * 64 + n * 16 + lane15];

#pragma unroll
    for (int m = 0; m < 8; ++m) {
#pragma unroll
        for (int r = 0; r < 4; ++r) {
            int gr = crow0 + wr * 128 + m * 16 + crow4 + r;
            if (gr >= nend) continue;
            int tok = ctok[gr];
            float* orow = out + (size_t)tok * DDIM + col0 + wc * 64 + lane15;
#pragma unroll
            for (int n = 0; n < 4; ++n)
                orow[n * 16] = acc[m][n][r] + bv[n];
        }
    }
}

extern "C" void kernel_launch(void* const* d_in, const int* in_sizes, int n_in,
                              void* d_out, int out_size, void* d_ws, size_t ws_size,
                              hipStream_t stream) {
    const float* actions = (const float*)d_in[0];
    const int*   atype   = (const int*)d_in[1];
    const float* W       = (const float*)d_in[2];
    const float* bias    = (const float*)d_in[3];
    float* out = (float*)d_out;

    int* wsi = (int*)d_ws;
    unsigned short* Abf = (unsigned short*)((char*)d_ws + WS_ABF_B);
    unsigned short* Wbf = (unsigned short*)((char*)d_ws + WS_WBF_B);

    route_k<<<1, 1024, 0, stream>>>(atype, wsi);
    fusedconv_k<<<4096 + 1792, 256, 0, stream>>>(actions, wsi, W, Wbf, Abf, out);
    gemm_k<<<NYMAX * 4, 512, 0, stream>>>(Abf, Wbf, bias, out, wsi);
}

// Round 8
// 85.993 us; speedup vs baseline: 1.1188x; 1.0258x over previous
//
#include <hip/hip_runtime.h>

// B=32, L=512, D=1024; 7 linear experts + identity, routed per token.
// Pipeline: route (fused count+offsets+slot, 1 wg) -> fusedconv (rowconv +
// convW) -> bf16 MFMA GEMM, 256x256 tile, 8 waves (2Mx4N, 128x64/wave),
// BK=64, XOR-swizzled LDS, DISTINCT-ARRAY double-buffer (compile-time
// buffer selection so the waitcnt legalizer can prove no LDS aliasing ->
// counted vmcnt(8) survives), raw s_barrier phases, setprio, XCD map.

#define NTOK 16384
#define DDIM 1024
#define NEXP 7
#define BM 256
#define BN 256
#define BK 64
#define NKT (DDIM / BK)
#define NYMAX 72              // 9 per XCD * 8

// ws layout (int indices / byte offsets)
#define WI_OFFS   16          // [8]
#define WI_NTILES 32
#define WI_TABLE  64          // [72][2] {expert, crow0}
#define WI_CTOK   512         // [16384] slot -> token
#define WI_SMAP   (512 + 16384) // [16384] token -> slot (-1 = identity)
#define WS_ABF_B  1048576                       // 32 MB bf16 A (compact)
#define WS_WBF_B  (WS_ABF_B + NTOK * DDIM * 2)  // 14 MB bf16 W

typedef __attribute__((ext_vector_type(8))) short short8;
typedef __attribute__((ext_vector_type(4))) float f32x4;

__device__ __forceinline__ unsigned short f2bf(float f) {
    unsigned u = __float_as_uint(f);
    u += 0x7fff + ((u >> 16) & 1);
    return (unsigned short)(u >> 16);
}

__device__ __forceinline__ void gload16(const void* g, void* l) {
    __builtin_amdgcn_global_load_lds(
        (const __attribute__((address_space(1))) void*)g,
        (__attribute__((address_space(3))) void*)l, 16, 0, 0);
}

// Single workgroup: per-wave histogram -> prefix/table -> slot scatter.
__global__ __launch_bounds__(1024) void route_k(
    const int* __restrict__ type, int* __restrict__ wsi) {
    __shared__ int h[16][8];
    __shared__ int cur[16][NEXP];
    const int tid = threadIdx.x, wave = tid >> 6;

    if (tid < 128) ((int*)h)[tid] = 0;
    __syncthreads();

    int kv[16];
#pragma unroll
    for (int i = 0; i < 16; ++i) {
        kv[i] = type[i * 1024 + tid];
        if (kv[i] > 0) atomicAdd(&h[wave][kv[i]], 1);
    }
    __syncthreads();

    if (tid == 0) {
        int acc = 0, t = 0;
        for (int e = 0; e < NEXP; ++e) {
            wsi[WI_OFFS + e] = acc;
            int run = acc;
            for (int w = 0; w < 16; ++w) { cur[w][e] = run; run += h[w][e + 1]; }
            int nt = (run - acc + BM - 1) >> 8;
            for (int i = 0; i < nt; ++i) {
                wsi[WI_TABLE + 2 * t] = e;
                wsi[WI_TABLE + 2 * t + 1] = acc + i * BM;
                ++t;
            }
            acc = run;
        }
        wsi[WI_OFFS + NEXP] = acc;
        wsi[WI_NTILES] = t;
    }
    __syncthreads();

#pragma unroll
    for (int i = 0; i < 16; ++i) {
        int t = i * 1024 + tid, s = -1;
        if (kv[i] > 0) {
            s = atomicAdd(&cur[wave][kv[i] - 1], 1);
            wsi[WI_CTOK + s] = t;
        }
        wsi[WI_SMAP + t] = s;
    }
}

// blocks 0..4095: per-row gather+convert/identity; blocks 4096..5887: W conv.
__global__ __launch_bounds__(256) void fusedconv_k(
    const float* __restrict__ A, const int* __restrict__ wsi,
    const float* __restrict__ W, unsigned short* __restrict__ Wbf,
    unsigned short* __restrict__ Abf, float* __restrict__ out) {
    const int bid = blockIdx.x, tid = threadIdx.x;
    if (bid < 4096) {
        int wave = tid >> 6, lane = tid & 63;
        int t = bid * 4 + wave;
        int s = wsi[WI_SMAP + t];
        const float4* src = (const float4*)(A + (size_t)t * DDIM);
        if (s < 0) {
            float4* d = (float4*)(out + (size_t)t * DDIM);
#pragma unroll
            for (int j = 0; j < 4; ++j) d[lane + j * 64] = src[lane + j * 64];
        } else {
            float4 v0 = src[lane * 4 + 0], v1 = src[lane * 4 + 1];
            float4 v2 = src[lane * 4 + 2], v3 = src[lane * 4 + 3];
            short8 h0, h1;
            h0[0]=f2bf(v0.x); h0[1]=f2bf(v0.y); h0[2]=f2bf(v0.z); h0[3]=f2bf(v0.w);
            h0[4]=f2bf(v1.x); h0[5]=f2bf(v1.y); h0[6]=f2bf(v1.z); h0[7]=f2bf(v1.w);
            h1[0]=f2bf(v2.x); h1[1]=f2bf(v2.y); h1[2]=f2bf(v2.z); h1[3]=f2bf(v2.w);
            h1[4]=f2bf(v3.x); h1[5]=f2bf(v3.y); h1[6]=f2bf(v3.z); h1[7]=f2bf(v3.w);
            unsigned short* d = Abf + (size_t)s * DDIM + lane * 16;
            *(short8*)d = h0;
            *(short8*)(d + 8) = h1;
        }
    } else {
        size_t i = ((size_t)(bid - 4096) * 256 + tid) * 16;
        const float4* src = (const float4*)(W + i);
        float4 v0 = src[0], v1 = src[1], v2 = src[2], v3 = src[3];
        short8 h0, h1;
        h0[0]=f2bf(v0.x); h0[1]=f2bf(v0.y); h0[2]=f2bf(v0.z); h0[3]=f2bf(v0.w);
        h0[4]=f2bf(v1.x); h0[5]=f2bf(v1.y); h0[6]=f2bf(v1.z); h0[7]=f2bf(v1.w);
        h1[0]=f2bf(v2.x); h1[1]=f2bf(v2.y); h1[2]=f2bf(v2.z); h1[3]=f2bf(v2.w);
        h1[4]=f2bf(v3.x); h1[5]=f2bf(v3.y); h1[6]=f2bf(v3.z); h1[7]=f2bf(v3.w);
        *(short8*)(Wbf + i) = h0;
        *(short8*)(Wbf + i + 8) = h1;
    }
}

#define LDA8(CA, SL)                                               \
    _Pragma("unroll")                                              \
    for (int m = 0; m < 8; ++m)                                    \
        a8[m] = *(const short8*)((const char*)CA + wr * 16384 +    \
                                 lane15 * 128 + m * 2048 + (SL));

#define LDB2(CB, N0, SL)                                           \
    bA = *(const short8*)((const char*)CB + wc * 8192 +            \
                          lane15 * 128 + (N0) * 2048 + (SL));      \
    bB = *(const short8*)((const char*)CB + wc * 8192 +            \
                          lane15 * 128 + ((N0) + 1) * 2048 + (SL));

#define MFMA_PHASE(N0, N1)                                         \
    __builtin_amdgcn_s_barrier();                                  \
    asm volatile("s_waitcnt lgkmcnt(0)" ::: "memory");             \
    __builtin_amdgcn_sched_barrier(0);                             \
    __builtin_amdgcn_s_setprio(1);                                 \
    _Pragma("unroll")                                              \
    for (int m = 0; m < 8; ++m) {                                  \
        acc[m][N0] = __builtin_amdgcn_mfma_f32_16x16x32_bf16(      \
            a8[m], bA, acc[m][N0], 0, 0, 0);                       \
        acc[m][N1] = __builtin_amdgcn_mfma_f32_16x16x32_bf16(      \
            a8[m], bB, acc[m][N1], 0, 0, 0);                       \
    }                                                              \
    __builtin_amdgcn_s_setprio(0);                                 \
    __builtin_amdgcn_s_barrier();

// One K-tile: stage next tile into NA/NB (distinct arrays -> provably no
// alias with CA/CB reads -> no legalizer vmcnt(0)), counted vmcnt(8) gate,
// then 4 lockstep phases of ds_read + 16 MFMA.
#define KTILE(CA, CB, NA, NB, KT)                                  \
    do {                                                           \
        if ((KT) + 1 < NKT) {                                      \
            const int ke_ = ((KT) + 1) * BK;                       \
            _Pragma("unroll")                                      \
            for (int q = 0; q < 4; ++q)                            \
                gload16(aSrc[q] + ke_,                             \
                        (char*)NA + wave * 1024 + q * 8192);       \
            _Pragma("unroll")                                      \
            for (int q = 0; q < 4; ++q)                            \
                gload16(bSrc[q] + ke_,                             \
                        (char*)NB + wave * 1024 + q * 8192);       \
            asm volatile("s_waitcnt vmcnt(8)" ::: "memory");       \
        } else {                                                   \
            asm volatile("s_waitcnt vmcnt(0)" ::: "memory");       \
        }                                                          \
        __builtin_amdgcn_s_barrier();                              \
        {                                                          \
            short8 a8[8], bA, bB;                                  \
            LDA8(CA, sl0); LDB2(CB, 0, sl0);                       \
            MFMA_PHASE(0, 1);                                      \
            LDB2(CB, 2, sl0);                                      \
            MFMA_PHASE(2, 3);                                      \
            LDA8(CA, sl1); LDB2(CB, 2, sl1);                       \
            MFMA_PHASE(2, 3);                                      \
            LDB2(CB, 0, sl1);                                      \
            MFMA_PHASE(0, 1);                                      \
        }                                                          \
    } while (0)

__global__ __launch_bounds__(512, 2) void gemm_k(
    const unsigned short* __restrict__ Abf,
    const unsigned short* __restrict__ Wbf,
    const float* __restrict__ bias, float* __restrict__ out,
    const int* __restrict__ wsi) {
    // XCD-interleaved: c = bid&7 = XCD; ty = (j>>2)*8+c, tx = j&3.
    const int bid = blockIdx.x;
    const int c = bid & 7, j = bid >> 3;
    const int ty = (j >> 2) * 8 + c;
    const int tx = j & 3;
    if (ty >= wsi[WI_NTILES]) return;
    const int* offs = wsi + WI_OFFS;
    const int* tab  = wsi + WI_TABLE;
    const int* ctok = wsi + WI_CTOK;
    const int e     = tab[2 * ty];
    const int crow0 = tab[2 * ty + 1];
    const int nend  = offs[e + 1];
    const int col0  = tx * BN;

    // 4 DISTINCT LDS arrays (compile-time dbuf selection; no alias hazards).
    // XOR-swizzled: row r chunk-slot s (16B) holds global chunk s^(r&7).
    __shared__ unsigned short As0[BM * BK];   // 32 KB each
    __shared__ unsigned short As1[BM * BK];
    __shared__ unsigned short Bs0[BM * BK];
    __shared__ unsigned short Bs1[BM * BK];

    const int tid = threadIdx.x, lane = tid & 63, wave = tid >> 6;
    const int wr = wave >> 2, wc = wave & 3;     // 2M x 4N; wave-tile 128x64
    const int lane15 = lane & 15;

    // staging: per wave 4 rounds x (8 rows x 8 chunks); lane -> (row,chunk)
    const int srow = lane >> 3;                          // 0..7
    const int schunk = ((lane & 7) ^ srow) * 8;          // inverse-swizzled src

    const unsigned short* Wb = Wbf + (size_t)e * DDIM * DDIM;
    const unsigned short* aSrc[4];
    const unsigned short* bSrc[4];
#pragma unroll
    for (int q = 0; q < 4; ++q) {
        int r = min(crow0 + q * 64 + wave * 8 + srow, NTOK - 1);
        aSrc[q] = Abf + (size_t)r * DDIM + schunk;
        bSrc[q] = Wb + (size_t)(col0 + q * 64 + wave * 8 + srow) * DDIM + schunk;
    }

    // swizzled ds_read slot byte-offsets for ks=0 / ks=1
    const int sl0 = (((lane >> 4)) ^ (lane & 7)) * 16;
    const int sl1 = ((4 | (lane >> 4)) ^ (lane & 7)) * 16;

    f32x4 acc[8][4];
#pragma unroll
    for (int m = 0; m < 8; ++m)
#pragma unroll
        for (int n = 0; n < 4; ++n) acc[m][n] = (f32x4){0.f, 0.f, 0.f, 0.f};

    // prologue: stage K-tile 0 into buf 0
#pragma unroll
    for (int q = 0; q < 4; ++q)
        gload16(aSrc[q], (char*)As0 + wave * 1024 + q * 8192);
#pragma unroll
    for (int q = 0; q < 4; ++q)
        gload16(bSrc[q], (char*)Bs0 + wave * 1024 + q * 8192);

    for (int kt2 = 0; kt2 < NKT / 2; ++kt2) {
        KTILE(As0, Bs0, As1, Bs1, 2 * kt2);
        KTILE(As1, Bs1, As0, Bs0, 2 * kt2 + 1);
    }

    // epilogue: bias + gathered store (C/D: col=lane&15, row=(lane>>4)*4+r)
    const int crow4 = (lane >> 4) * 4;
    float bv[4];
#pragma unroll
    for (int n = 0; n < 4; ++n)
        bv[n] = bias[e * DDIM + col0 + wc * 64 + n * 16 + lane15];

#pragma unroll
    for (int m = 0; m < 8; ++m) {
#pragma unroll
        for (int r = 0; r < 4; ++r) {
            int gr = crow0 + wr * 128 + m * 16 + crow4 + r;
            if (gr >= nend) continue;
            int tok = ctok[gr];
            float* orow = out + (size_t)tok * DDIM + col0 + wc * 64 + lane15;
#pragma unroll
            for (int n = 0; n < 4; ++n)
                orow[n * 16] = acc[m][n][r] + bv[n];
        }
    }
}

extern "C" void kernel_launch(void* const* d_in, const int* in_sizes, int n_in,
                              void* d_out, int out_size, void* d_ws, size_t ws_size,
                              hipStream_t stream) {
    const float* actions = (const float*)d_in[0];
    const int*   atype   = (const int*)d_in[1];
    const float* W       = (const float*)d_in[2];
    const float* bias    = (const float*)d_in[3];
    float* out = (float*)d_out;

    int* wsi = (int*)d_ws;
    unsigned short* Abf = (unsigned short*)((char*)d_ws + WS_ABF_B);
    unsigned short* Wbf = (unsigned short*)((char*)d_ws + WS_WBF_B);

    route_k<<<1, 1024, 0, stream>>>(atype, wsi);
    fusedconv_k<<<4096 + 1792, 256, 0, stream>>>(actions, wsi, W, Wbf, Abf, out);
    gemm_k<<<NYMAX * 4, 512, 0, stream>>>(Abf, Wbf, bias, out, wsi);
}

// Round 9
// 81.646 us; speedup vs baseline: 1.1783x; 1.0532x over previous
//
#include <hip/hip_runtime.h>

// B=32, L=512, D=1024; 7 linear experts + identity, routed per token.
// Pipeline: route (1 wg) -> fusedconv (rowconv + convW) -> bf16 MFMA GEMM:
// 256x256 tile, 8 waves (2Mx4N, 128x64/wave), BK=64, XOR-swizzled LDS,
// distinct-array double-buffer, ONE barrier per K-tile (intra-tile barriers
// removed: reads hit buf[cur], gloads write the other distinct buffer ->
// no hazard; per-wave lgkm drain + tile-end vmcnt(0)+barrier is sufficient),
// compiler-placed lgkm waits, setprio around MFMA bursts, XCD-chunked map.

#define NTOK 16384
#define DDIM 1024
#define NEXP 7
#define BM 256
#define BN 256
#define BK 64
#define NKT (DDIM / BK)
#define NYMAX 72              // 9 per XCD * 8

// ws layout (int indices / byte offsets)
#define WI_OFFS   16          // [8]
#define WI_NTILES 32
#define WI_TABLE  64          // [72][2] {expert, crow0}
#define WI_CTOK   512         // [16384] slot -> token
#define WI_SMAP   (512 + 16384) // [16384] token -> slot (-1 = identity)
#define WS_ABF_B  1048576                       // 32 MB bf16 A (compact)
#define WS_WBF_B  (WS_ABF_B + NTOK * DDIM * 2)  // 14 MB bf16 W

typedef __attribute__((ext_vector_type(8))) short short8;
typedef __attribute__((ext_vector_type(4))) float f32x4;

__device__ __forceinline__ unsigned short f2bf(float f) {
    unsigned u = __float_as_uint(f);
    u += 0x7fff + ((u >> 16) & 1);
    return (unsigned short)(u >> 16);
}

__device__ __forceinline__ void gload16(const void* g, void* l) {
    __builtin_amdgcn_global_load_lds(
        (const __attribute__((address_space(1))) void*)g,
        (__attribute__((address_space(3))) void*)l, 16, 0, 0);
}

// Single workgroup: per-wave histogram -> prefix/table -> slot scatter.
__global__ __launch_bounds__(1024) void route_k(
    const int* __restrict__ type, int* __restrict__ wsi) {
    __shared__ int h[16][8];
    __shared__ int cur[16][NEXP];
    const int tid = threadIdx.x, wave = tid >> 6;

    if (tid < 128) ((int*)h)[tid] = 0;
    __syncthreads();

    int kv[16];
#pragma unroll
    for (int i = 0; i < 16; ++i) {
        kv[i] = type[i * 1024 + tid];
        if (kv[i] > 0) atomicAdd(&h[wave][kv[i]], 1);
    }
    __syncthreads();

    if (tid == 0) {
        int acc = 0, t = 0;
        for (int e = 0; e < NEXP; ++e) {
            wsi[WI_OFFS + e] = acc;
            int run = acc;
            for (int w = 0; w < 16; ++w) { cur[w][e] = run; run += h[w][e + 1]; }
            int nt = (run - acc + BM - 1) >> 8;
            for (int i = 0; i < nt; ++i) {
                wsi[WI_TABLE + 2 * t] = e;
                wsi[WI_TABLE + 2 * t + 1] = acc + i * BM;
                ++t;
            }
            acc = run;
        }
        wsi[WI_OFFS + NEXP] = acc;
        wsi[WI_NTILES] = t;
    }
    __syncthreads();

#pragma unroll
    for (int i = 0; i < 16; ++i) {
        int t = i * 1024 + tid, s = -1;
        if (kv[i] > 0) {
            s = atomicAdd(&cur[wave][kv[i] - 1], 1);
            wsi[WI_CTOK + s] = t;
        }
        wsi[WI_SMAP + t] = s;
    }
}

// blocks 0..4095: per-row gather+convert/identity; blocks 4096..5887: W conv.
__global__ __launch_bounds__(256) void fusedconv_k(
    const float* __restrict__ A, const int* __restrict__ wsi,
    const float* __restrict__ W, unsigned short* __restrict__ Wbf,
    unsigned short* __restrict__ Abf, float* __restrict__ out) {
    const int bid = blockIdx.x, tid = threadIdx.x;
    if (bid < 4096) {
        int wave = tid >> 6, lane = tid & 63;
        int t = bid * 4 + wave;
        int s = wsi[WI_SMAP + t];
        const float4* src = (const float4*)(A + (size_t)t * DDIM);
        if (s < 0) {
            float4* d = (float4*)(out + (size_t)t * DDIM);
#pragma unroll
            for (int j = 0; j < 4; ++j) d[lane + j * 64] = src[lane + j * 64];
        } else {
            float4 v0 = src[lane * 4 + 0], v1 = src[lane * 4 + 1];
            float4 v2 = src[lane * 4 + 2], v3 = src[lane * 4 + 3];
            short8 h0, h1;
            h0[0]=f2bf(v0.x); h0[1]=f2bf(v0.y); h0[2]=f2bf(v0.z); h0[3]=f2bf(v0.w);
            h0[4]=f2bf(v1.x); h0[5]=f2bf(v1.y); h0[6]=f2bf(v1.z); h0[7]=f2bf(v1.w);
            h1[0]=f2bf(v2.x); h1[1]=f2bf(v2.y); h1[2]=f2bf(v2.z); h1[3]=f2bf(v2.w);
            h1[4]=f2bf(v3.x); h1[5]=f2bf(v3.y); h1[6]=f2bf(v3.z); h1[7]=f2bf(v3.w);
            unsigned short* d = Abf + (size_t)s * DDIM + lane * 16;
            *(short8*)d = h0;
            *(short8*)(d + 8) = h1;
        }
    } else {
        size_t i = ((size_t)(bid - 4096) * 256 + tid) * 16;
        const float4* src = (const float4*)(W + i);
        float4 v0 = src[0], v1 = src[1], v2 = src[2], v3 = src[3];
        short8 h0, h1;
        h0[0]=f2bf(v0.x); h0[1]=f2bf(v0.y); h0[2]=f2bf(v0.z); h0[3]=f2bf(v0.w);
        h0[4]=f2bf(v1.x); h0[5]=f2bf(v1.y); h0[6]=f2bf(v1.z); h0[7]=f2bf(v1.w);
        h1[0]=f2bf(v2.x); h1[1]=f2bf(v2.y); h1[2]=f2bf(v2.z); h1[3]=f2bf(v2.w);
        h1[4]=f2bf(v3.x); h1[5]=f2bf(v3.y); h1[6]=f2bf(v3.z); h1[7]=f2bf(v3.w);
        *(short8*)(Wbf + i) = h0;
        *(short8*)(Wbf + i + 8) = h1;
    }
}

// One K-tile: read buf (Abase/Bbase) in two k-halves with compiler-placed
// lgkm waits; stage next tile into the OTHER distinct arrays; one
// vmcnt(0)+barrier gate per tile. rd2 issued after MFMA1 to cap VGPR.
#define TILE(Abase, Bbase, sNA, sNB, KT)                           \
    do {                                                           \
        short8 a1[8], b1[4];                                       \
        _Pragma("unroll")                                          \
        for (int m = 0; m < 8; ++m)                                \
            a1[m] = *(const short8*)(Abase + sl0 + m * 2048);      \
        _Pragma("unroll")                                          \
        for (int n = 0; n < 4; ++n)                                \
            b1[n] = *(const short8*)(Bbase + sl0 + n * 2048);      \
        if ((KT) + 1 < NKT) {                                      \
            const int ke_ = ((KT) + 1) * BK;                       \
            _Pragma("unroll")                                      \
            for (int q = 0; q < 4; ++q)                            \
                gload16(aSrc[q] + ke_, sNA + q * 8192);            \
            _Pragma("unroll")                                      \
            for (int q = 0; q < 4; ++q)                            \
                gload16(bSrc[q] + ke_, sNB + q * 8192);            \
        }                                                          \
        __builtin_amdgcn_s_setprio(1);                             \
        _Pragma("unroll")                                          \
        for (int m = 0; m < 8; ++m)                                \
            _Pragma("unroll")                                      \
            for (int n = 0; n < 4; ++n)                            \
                acc[m][n] = __builtin_amdgcn_mfma_f32_16x16x32_bf16(\
                    a1[m], b1[n], acc[m][n], 0, 0, 0);             \
        __builtin_amdgcn_s_setprio(0);                             \
        short8 a2[8], b2[4];                                       \
        _Pragma("unroll")                                          \
        for (int m = 0; m < 8; ++m)                                \
            a2[m] = *(const short8*)(Abase + sl1 + m * 2048);      \
        _Pragma("unroll")                                          \
        for (int n = 0; n < 4; ++n)                                \
            b2[n] = *(const short8*)(Bbase + sl1 + n * 2048);      \
        __builtin_amdgcn_s_setprio(1);                             \
        _Pragma("unroll")                                          \
        for (int m = 0; m < 8; ++m)                                \
            _Pragma("unroll")                                      \
            for (int n = 0; n < 4; ++n)                            \
                acc[m][n] = __builtin_amdgcn_mfma_f32_16x16x32_bf16(\
                    a2[m], b2[n], acc[m][n], 0, 0, 0);             \
        __builtin_amdgcn_s_setprio(0);                             \
        asm volatile("s_waitcnt vmcnt(0)" ::: "memory");           \
        __builtin_amdgcn_s_barrier();                              \
    } while (0)

__global__ __launch_bounds__(512, 2) void gemm_k(
    const unsigned short* __restrict__ Abf,
    const unsigned short* __restrict__ Wbf,
    const float* __restrict__ bias, float* __restrict__ out,
    const int* __restrict__ wsi) {
    // XCD-interleaved: c = bid&7 = XCD; ty = (j>>2)*8+c, tx = j&3.
    const int bid = blockIdx.x;
    const int c = bid & 7, j = bid >> 3;
    const int ty = (j >> 2) * 8 + c;
    const int tx = j & 3;
    if (ty >= wsi[WI_NTILES]) return;
    const int* offs = wsi + WI_OFFS;
    const int* tab  = wsi + WI_TABLE;
    const int* ctok = wsi + WI_CTOK;
    const int e     = tab[2 * ty];
    const int crow0 = tab[2 * ty + 1];
    const int nend  = offs[e + 1];
    const int col0  = tx * BN;

    // 4 distinct LDS arrays (compile-time dbuf; no alias hazards).
    // XOR-swizzled: row r chunk-slot s (16B) holds global chunk s^(r&7).
    __shared__ unsigned short As0[BM * BK];   // 32 KB each
    __shared__ unsigned short As1[BM * BK];
    __shared__ unsigned short Bs0[BM * BK];
    __shared__ unsigned short Bs1[BM * BK];

    const int tid = threadIdx.x, lane = tid & 63, wave = tid >> 6;
    const int wr = wave >> 2, wc = wave & 3;     // 2M x 4N; wave-tile 128x64
    const int lane15 = lane & 15;

    // staging: per wave 4 rounds x (8 rows x 8 chunks); lane -> (row,chunk)
    const int srow = lane >> 3;                          // 0..7
    const int schunk = ((lane & 7) ^ srow) * 8;          // inverse-swizzled src

    const unsigned short* Wb = Wbf + (size_t)e * DDIM * DDIM;
    const unsigned short* aSrc[4];
    const unsigned short* bSrc[4];
#pragma unroll
    for (int q = 0; q < 4; ++q) {
        int r = min(crow0 + q * 64 + wave * 8 + srow, NTOK - 1);
        aSrc[q] = Abf + (size_t)r * DDIM + schunk;
        bSrc[q] = Wb + (size_t)(col0 + q * 64 + wave * 8 + srow) * DDIM + schunk;
    }

    // ds_read bases (loop-invariant) + swizzled slot offsets for k-halves
    const int sl0 = (((lane >> 4)) ^ (lane & 7)) * 16;
    const int sl1 = ((4 | (lane >> 4)) ^ (lane & 7)) * 16;
    const char* aR0 = (const char*)As0 + wr * 16384 + lane15 * 128;
    const char* aR1 = (const char*)As1 + wr * 16384 + lane15 * 128;
    const char* bR0 = (const char*)Bs0 + wc * 8192 + lane15 * 128;
    const char* bR1 = (const char*)Bs1 + wc * 8192 + lane15 * 128;
    char* sA0 = (char*)As0 + wave * 1024;
    char* sA1 = (char*)As1 + wave * 1024;
    char* sB0 = (char*)Bs0 + wave * 1024;
    char* sB1 = (char*)Bs1 + wave * 1024;

    f32x4 acc[8][4];
#pragma unroll
    for (int m = 0; m < 8; ++m)
#pragma unroll
        for (int n = 0; n < 4; ++n) acc[m][n] = (f32x4){0.f, 0.f, 0.f, 0.f};

    // prologue: stage K-tile 0 into buf 0, gate
#pragma unroll
    for (int q = 0; q < 4; ++q) gload16(aSrc[q], sA0 + q * 8192);
#pragma unroll
    for (int q = 0; q < 4; ++q) gload16(bSrc[q], sB0 + q * 8192);
    asm volatile("s_waitcnt vmcnt(0)" ::: "memory");
    __builtin_amdgcn_s_barrier();

    for (int kt2 = 0; kt2 < NKT / 2; ++kt2) {
        TILE(aR0, bR0, sA1, sB1, 2 * kt2);
        TILE(aR1, bR1, sA0, sB0, 2 * kt2 + 1);
    }

    // epilogue: bias + gathered store (C/D: col=lane&15, row=(lane>>4)*4+r)
    const int crow4 = (lane >> 4) * 4;
    float bv[4];
#pragma unroll
    for (int n = 0; n < 4; ++n)
        bv[n] = bias[e * DDIM + col0 + wc * 64 + n * 16 + lane15];

#pragma unroll
    for (int m = 0; m < 8; ++m) {
#pragma unroll
        for (int r = 0; r < 4; ++r) {
            int gr = crow0 + wr * 128 + m * 16 + crow4 + r;
            if (gr >= nend) continue;
            int tok = ctok[gr];
            float* orow = out + (size_t)tok * DDIM + col0 + wc * 64 + lane15;
#pragma unroll
            for (int n = 0; n < 4; ++n)
                orow[n * 16] = acc[m][n][r] + bv[n];
        }
    }
}

extern "C" void kernel_launch(void* const* d_in, const int* in_sizes, int n_in,
                              void* d_out, int out_size, void* d_ws, size_t ws_size,
                              hipStream_t stream) {
    const float* actions = (const float*)d_in[0];
    const int*   atype   = (const int*)d_in[1];
    const float* W       = (const float*)d_in[2];
    const float* bias    = (const float*)d_in[3];
    float* out = (float*)d_out;

    int* wsi = (int*)d_ws;
    unsigned short* Abf = (unsigned short*)((char*)d_ws + WS_ABF_B);
    unsigned short* Wbf = (unsigned short*)((char*)d_ws + WS_WBF_B);

    route_k<<<1, 1024, 0, stream>>>(atype, wsi);
    fusedconv_k<<<4096 + 1792, 256, 0, stream>>>(actions, wsi, W, Wbf, Abf, out);
    gemm_k<<<NYMAX * 4, 512, 0, stream>>>(Abf, Wbf, bias, out, wsi);
}